// Round 1
// baseline (73.445 us; speedup 1.0000x reference)
//
#include <hip/hip_runtime.h>
#include <math.h>

#define HH 30
#define WWID 30
#define HW 900
#define SENTV 900
#define DD 256
#define MAXK 16
#define COMB_LD 272   // padded row stride for comb (68 float4)

__device__ __forceinline__ float gelu_exact(float x) {
    return 0.5f * x * (1.0f + erff(x * 0.70710678118654752440f));
}

__global__ __launch_bounds__(256) void ccce_fused(
    const float* __restrict__ grid_emb,
    const int* __restrict__ grid,
    const float* __restrict__ structure_rep,
    const float* __restrict__ W1, const float* __restrict__ b1,
    const float* __restrict__ W2, const float* __restrict__ b2,
    const float* __restrict__ Wp, const float* __restrict__ bp,
    const float* __restrict__ gvec, const float* __restrict__ bvec,
    const float* __restrict__ ortho_scale,
    float* __restrict__ out, int KS)
{
    const int b = blockIdx.x;
    const int tid = threadIdx.x;

    __shared__ int color_s[HW];
    __shared__ int lab_s[HW];
    __shared__ int changed_s;
    __shared__ int root_s[MAXK];
    __shared__ int nroot_s;
    __shared__ int by0[MAXK], by1[MAXK], bx0[MAXK], bx1[MAXK];
    __shared__ int sy[MAXK], sx[MAXK], shh[MAXK], sww[MAXK], scol[MAXK], sval[MAXK];
    __shared__ float4 comb4_s[MAXK * (COMB_LD/4)];
    __shared__ float4 hdn4_s[MAXK * (DD/4)];
    __shared__ __align__(16) float sn_s[DD];
    __shared__ float red_s[4];

    float* comb_s = (float*)comb4_s;

    // ---------- load grid, init labels ----------
    for (int i = tid; i < HW; i += 256) {
        int c = grid[b*HW + i];
        color_s[i] = c;
        lab_s[i] = (c > 0) ? i : SENTV;
    }
    __syncthreads();

    // ---------- CCL: min-label propagation + path compression ----------
    // Monotone-decreasing labels -> async updates converge to the unique
    // fixpoint (min linear index per 4-connected same-color component),
    // identical to the reference's nbr_min + pointer-jump loop.
    for (;;) {
        if (tid == 0) changed_s = 0;
        __syncthreads();
        for (int i = tid; i < HW; i += 256) {
            int c = color_s[i];
            if (c <= 0) continue;
            int m = lab_s[i];
            int r = i / WWID;
            int cc = i - r * WWID;
            if (r > 0       && color_s[i-WWID] == c) m = min(m, lab_s[i-WWID]);
            if (r < HH-1    && color_s[i+WWID] == c) m = min(m, lab_s[i+WWID]);
            if (cc > 0      && color_s[i-1]    == c) m = min(m, lab_s[i-1]);
            if (cc < WWID-1 && color_s[i+1]    == c) m = min(m, lab_s[i+1]);
            for (;;) { int p = lab_s[m]; if (p >= m) break; m = p; }
            if (m < lab_s[i]) { lab_s[i] = m; changed_s = 1; }
        }
        __syncthreads();
        int ch = changed_s;
        __syncthreads();
        if (!ch) break;
    }

    // ---------- first 16 roots in raster order (wave 0 ballot scan) ----------
    if (tid < 64) {
        int base = 0;
        for (int chk = 0; chk < 15; ++chk) {
            int cell = chk*64 + tid;
            bool isr = (cell < HW) && (color_s[cell] > 0) && (lab_s[cell] == cell);
            unsigned long long mask = __ballot(isr);
            int rank = base + __popcll(mask & ((1ull << tid) - 1ull));
            if (isr && rank < MAXK) root_s[rank] = cell;
            base += __popcll(mask);
        }
        if (tid == 0) nroot_s = base;
        if (tid < MAXK) { by0[tid]=HH; by1[tid]=-1; bx0[tid]=WWID; bx1[tid]=-1; }
    }
    __syncthreads();

    // ---------- bboxes via LDS atomics ----------
    const int nval = min(nroot_s, MAXK);
    for (int i = tid; i < HW; i += 256) {
        if (color_s[i] <= 0) continue;
        int L = lab_s[i];
        int s = -1;
        for (int k = 0; k < nval; ++k) if (root_s[k] == L) { s = k; break; }
        if (s >= 0) {
            int r = i / WWID;
            int cc = i - r * WWID;
            atomicMin(&by0[s], r); atomicMax(&by1[s], r);
            atomicMin(&bx0[s], cc); atomicMax(&bx1[s], cc);
        }
    }
    __syncthreads();
    if (tid < MAXK) {
        int v = (tid < nval) ? 1 : 0;
        sval[tid] = v;
        if (v) {
            sy[tid] = by0[tid]; sx[tid] = bx0[tid];
            shh[tid] = by1[tid] + 1 - by0[tid];
            sww[tid] = bx1[tid] + 1 - bx0[tid];
            scol[tid] = color_s[root_s[tid]];
        } else { sy[tid]=0; sx[tid]=0; shh[tid]=1; sww[tid]=1; scol[tid]=0; }
    }
    __syncthreads();

    // ---------- bbox pooling (direct sums == SAT) + bbox feats ----------
    for (int k = 0; k < MAXK; ++k) {
        float pv = 0.f;
        if (sval[k]) {
            int y=sy[k], x=sx[k], h=shh[k], w=sww[k];
            float sum = 0.f;
            for (int yy = y; yy < y + h; ++yy) {
                const float* p = grid_emb + ((size_t)(b*HH + yy)*WWID + x)*DD + tid;
                for (int xx = 0; xx < w; ++xx) sum += p[(size_t)xx*DD];
            }
            pv = sum / (float)(h*w);
        }
        comb_s[k*COMB_LD + tid] = pv;   // d = tid
    }
    if (tid < 5) {
        for (int k = 0; k < MAXK; ++k) {
            float f = 0.f;
            if (sval[k]) {
                switch (tid) {
                    case 0: f = (float)scol[k] / 9.0f;  break;
                    case 1: f = (float)sx[k]  / 30.0f;  break;
                    case 2: f = (float)sy[k]  / 30.0f;  break;
                    case 3: f = (float)sww[k] / 30.0f;  break;
                    case 4: f = (float)shh[k] / 30.0f;  break;
                }
            }
            comb_s[k*COMB_LD + 256 + tid] = f;
        }
    }

    // ---------- structure mean + L2-normalize -> sn_s ----------
    {
        float s = 0.f;
        const float* sr = structure_rep + (size_t)b*KS*DD + tid;
        for (int j = 0; j < KS; ++j) s += sr[(size_t)j*DD];
        s *= (1.0f / (float)KS);
        float ss = s*s;
        #pragma unroll
        for (int off = 32; off > 0; off >>= 1) ss += __shfl_xor(ss, off);
        if ((tid & 63) == 0) red_s[tid >> 6] = ss;
        __syncthreads();
        float nrm = sqrtf(red_s[0] + red_s[1] + red_s[2] + red_s[3]);
        sn_s[tid] = s / fmaxf(nrm, 1e-8f);
    }
    __syncthreads();   // comb_s, sn_s visible to all

    // ---------- register-tiled MLP: wave wv owns rows 4wv..4wv+3 ----------
    const int tx = tid & 63;
    const int wv = tid >> 6;
    const int c0 = tx * 4;
    const int r0 = wv * 4;

    float acc[4][4];
    #pragma unroll
    for (int j=0;j<4;++j) { acc[j][0]=0.f; acc[j][1]=0.f; acc[j][2]=0.f; acc[j][3]=0.f; }

    // GEMM1: hdn = gelu(comb @ W1 + b1), K = 261
    for (int f4 = 0; f4 < 65; ++f4) {
        float4 bb0 = *(const float4*)(W1 + (size_t)(f4*4+0)*DD + c0);
        float4 bb1 = *(const float4*)(W1 + (size_t)(f4*4+1)*DD + c0);
        float4 bb2 = *(const float4*)(W1 + (size_t)(f4*4+2)*DD + c0);
        float4 bb3 = *(const float4*)(W1 + (size_t)(f4*4+3)*DD + c0);
        #pragma unroll
        for (int j = 0; j < 4; ++j) {
            float4 a = comb4_s[(r0+j)*(COMB_LD/4) + f4];
            acc[j][0] += a.x*bb0.x + a.y*bb1.x + a.z*bb2.x + a.w*bb3.x;
            acc[j][1] += a.x*bb0.y + a.y*bb1.y + a.z*bb2.y + a.w*bb3.y;
            acc[j][2] += a.x*bb0.z + a.y*bb1.z + a.z*bb2.z + a.w*bb3.z;
            acc[j][3] += a.x*bb0.w + a.y*bb1.w + a.z*bb2.w + a.w*bb3.w;
        }
    }
    {   // tail f = 260
        float4 bt = *(const float4*)(W1 + (size_t)260*DD + c0);
        #pragma unroll
        for (int j = 0; j < 4; ++j) {
            float a = comb_s[(r0+j)*COMB_LD + 260];
            acc[j][0]+=a*bt.x; acc[j][1]+=a*bt.y; acc[j][2]+=a*bt.z; acc[j][3]+=a*bt.w;
        }
    }
    {
        float4 b1v = *(const float4*)(b1 + c0);
        #pragma unroll
        for (int j = 0; j < 4; ++j) {
            float4 h;
            h.x = gelu_exact(acc[j][0] + b1v.x);
            h.y = gelu_exact(acc[j][1] + b1v.y);
            h.z = gelu_exact(acc[j][2] + b1v.z);
            h.w = gelu_exact(acc[j][3] + b1v.w);
            hdn4_s[(r0+j)*(DD/4) + tx] = h;
        }
    }
    __syncthreads();

    // GEMM2: obj = (hdn @ W2 + b2) * valid, K = 256
    #pragma unroll
    for (int j=0;j<4;++j) { acc[j][0]=0.f; acc[j][1]=0.f; acc[j][2]=0.f; acc[j][3]=0.f; }
    for (int f4 = 0; f4 < 64; ++f4) {
        float4 bb0 = *(const float4*)(W2 + (size_t)(f4*4+0)*DD + c0);
        float4 bb1 = *(const float4*)(W2 + (size_t)(f4*4+1)*DD + c0);
        float4 bb2 = *(const float4*)(W2 + (size_t)(f4*4+2)*DD + c0);
        float4 bb3 = *(const float4*)(W2 + (size_t)(f4*4+3)*DD + c0);
        #pragma unroll
        for (int j = 0; j < 4; ++j) {
            float4 a = hdn4_s[(r0+j)*(DD/4) + f4];
            acc[j][0] += a.x*bb0.x + a.y*bb1.x + a.z*bb2.x + a.w*bb3.x;
            acc[j][1] += a.x*bb0.y + a.y*bb1.y + a.z*bb2.y + a.w*bb3.y;
            acc[j][2] += a.x*bb0.z + a.y*bb1.z + a.z*bb2.z + a.w*bb3.z;
            acc[j][3] += a.x*bb0.w + a.y*bb1.w + a.z*bb2.w + a.w*bb3.w;
        }
    }
    float obj[4][4];
    {
        float4 b2v = *(const float4*)(b2 + c0);
        #pragma unroll
        for (int j = 0; j < 4; ++j) {
            float vm = sval[r0+j] ? 1.f : 0.f;
            obj[j][0] = (acc[j][0] + b2v.x) * vm;
            obj[j][1] = (acc[j][1] + b2v.y) * vm;
            obj[j][2] = (acc[j][2] + b2v.z) * vm;
            obj[j][3] = (acc[j][3] + b2v.w) * vm;
        }
    }
    __syncthreads();   // all reads of hdn4_s done before overwrite with co

    // dot + orthogonal rejection -> co (stored back into hdn4_s)
    {
        float ortho = ortho_scale[0];
        float4 snv = *(const float4*)(sn_s + c0);
        #pragma unroll
        for (int j = 0; j < 4; ++j) {
            float p = obj[j][0]*snv.x + obj[j][1]*snv.y + obj[j][2]*snv.z + obj[j][3]*snv.w;
            #pragma unroll
            for (int off = 32; off > 0; off >>= 1) p += __shfl_xor(p, off);
            float4 co;
            co.x = (obj[j][0] - p*snv.x) * ortho;
            co.y = (obj[j][1] - p*snv.y) * ortho;
            co.z = (obj[j][2] - p*snv.z) * ortho;
            co.w = (obj[j][3] - p*snv.w) * ortho;
            hdn4_s[(r0+j)*(DD/4) + tx] = co;
        }
    }
    __syncthreads();

    // GEMM3: co @ Wp + bp, then LayerNorm * gamma + beta
    #pragma unroll
    for (int j=0;j<4;++j) { acc[j][0]=0.f; acc[j][1]=0.f; acc[j][2]=0.f; acc[j][3]=0.f; }
    for (int f4 = 0; f4 < 64; ++f4) {
        float4 bb0 = *(const float4*)(Wp + (size_t)(f4*4+0)*DD + c0);
        float4 bb1 = *(const float4*)(Wp + (size_t)(f4*4+1)*DD + c0);
        float4 bb2 = *(const float4*)(Wp + (size_t)(f4*4+2)*DD + c0);
        float4 bb3 = *(const float4*)(Wp + (size_t)(f4*4+3)*DD + c0);
        #pragma unroll
        for (int j = 0; j < 4; ++j) {
            float4 a = hdn4_s[(r0+j)*(DD/4) + f4];
            acc[j][0] += a.x*bb0.x + a.y*bb1.x + a.z*bb2.x + a.w*bb3.x;
            acc[j][1] += a.x*bb0.y + a.y*bb1.y + a.z*bb2.y + a.w*bb3.y;
            acc[j][2] += a.x*bb0.z + a.y*bb1.z + a.z*bb2.z + a.w*bb3.z;
            acc[j][3] += a.x*bb0.w + a.y*bb1.w + a.z*bb2.w + a.w*bb3.w;
        }
    }
    {
        float4 bpv = *(const float4*)(bp + c0);
        float4 gv  = *(const float4*)(gvec + c0);
        float4 bv  = *(const float4*)(bvec + c0);
        #pragma unroll
        for (int j = 0; j < 4; ++j) {
            float v0 = acc[j][0] + bpv.x;
            float v1 = acc[j][1] + bpv.y;
            float v2 = acc[j][2] + bpv.z;
            float v3 = acc[j][3] + bpv.w;
            float sm = v0+v1+v2+v3;
            float sq = v0*v0+v1*v1+v2*v2+v3*v3;
            #pragma unroll
            for (int off = 32; off > 0; off >>= 1) {
                sm += __shfl_xor(sm, off);
                sq += __shfl_xor(sq, off);
            }
            float mu  = sm * (1.0f/256.0f);
            float var = fmaxf(sq * (1.0f/256.0f) - mu*mu, 0.0f);
            float rstd = 1.0f / sqrtf(var + 1e-5f);
            float4 o;
            o.x = (v0-mu)*rstd*gv.x + bv.x;
            o.y = (v1-mu)*rstd*gv.y + bv.y;
            o.z = (v2-mu)*rstd*gv.z + bv.z;
            o.w = (v3-mu)*rstd*gv.w + bv.w;
            *(float4*)(out + ((size_t)b*MAXK + (r0+j))*DD + c0) = o;
        }
    }
}

extern "C" void kernel_launch(void* const* d_in, const int* in_sizes, int n_in,
                              void* d_out, int out_size, void* d_ws, size_t ws_size,
                              hipStream_t stream) {
    const float* grid_emb = (const float*)d_in[0];
    const int*   grid     = (const int*)d_in[1];
    const float* srep     = (const float*)d_in[2];
    const float* W1v = (const float*)d_in[3];
    const float* b1v = (const float*)d_in[4];
    const float* W2v = (const float*)d_in[5];
    const float* b2v = (const float*)d_in[6];
    const float* Wpv = (const float*)d_in[7];
    const float* bpv = (const float*)d_in[8];
    const float* gv  = (const float*)d_in[9];
    const float* bv  = (const float*)d_in[10];
    const float* osv = (const float*)d_in[11];
    float* out = (float*)d_out;

    const int B  = in_sizes[1] / HW;
    const int KS = in_sizes[2] / (B * DD);

    hipLaunchKernelGGL(ccce_fused, dim3(B), dim3(256), 0, stream,
                       grid_emb, grid, srep, W1v, b1v, W2v, b2v, Wpv, bpv,
                       gv, bv, osv, out, KS);
}

// Round 2
// 67.248 us; speedup vs baseline: 1.0921x; 1.0921x over previous
//
#include <hip/hip_runtime.h>
#include <math.h>

#define HH 30
#define WWID 30
#define HW 900
#define SENTV 900
#define DD 256
#define MAXK 16
#define COMB_LD 264   // 4 rows of comb, padded

__device__ __forceinline__ float gelu_exact(float x) {
    return 0.5f * x * (1.0f + erff(x * 0.70710678118654752440f));
}

__device__ __forceinline__ float rdlane(float v, int i) {
    return __int_as_float(__builtin_amdgcn_readlane(__float_as_int(v), i));
}

// One K=256 GEMM row-pass: this wave's A-row is distributed across lanes
// (thread tx holds chunk a = A[4tx..4tx+3]); broadcast via v_readlane.
// Thread computes 4 output cols c0..c0+3. No LDS, no barriers.
__device__ __forceinline__ float4 gemm_row_k256(const float4 a,
                                                const float* __restrict__ Wm,
                                                int c0) {
    float ax = 0.f, ay = 0.f, az = 0.f, aw = 0.f;
    #pragma unroll 4
    for (int i = 0; i < 64; ++i) {
        const float* wp = Wm + (size_t)(4 * i) * DD + c0;
        float4 b0 = *(const float4*)(wp);
        float4 b1 = *(const float4*)(wp + DD);
        float4 b2 = *(const float4*)(wp + 2 * DD);
        float4 b3 = *(const float4*)(wp + 3 * DD);
        float a0 = rdlane(a.x, i);
        float a1 = rdlane(a.y, i);
        float a2 = rdlane(a.z, i);
        float a3 = rdlane(a.w, i);
        ax += a0 * b0.x + a1 * b1.x + a2 * b2.x + a3 * b3.x;
        ay += a0 * b0.y + a1 * b1.y + a2 * b2.y + a3 * b3.y;
        az += a0 * b0.z + a1 * b1.z + a2 * b2.z + a3 * b3.z;
        aw += a0 * b0.w + a1 * b1.w + a2 * b2.w + a3 * b3.w;
    }
    return make_float4(ax, ay, az, aw);
}

__global__ __launch_bounds__(256) void ccce_fused(
    const float* __restrict__ grid_emb,
    const int* __restrict__ grid,
    const float* __restrict__ structure_rep,
    const float* __restrict__ W1, const float* __restrict__ b1,
    const float* __restrict__ W2, const float* __restrict__ b2,
    const float* __restrict__ Wp, const float* __restrict__ bp,
    const float* __restrict__ gvec, const float* __restrict__ bvec,
    const float* __restrict__ ortho_scale,
    float* __restrict__ out, int KS)
{
    const int b = blockIdx.x >> 2;   // batch
    const int q = blockIdx.x & 3;    // slot quarter: rows 4q..4q+3
    const int tid = threadIdx.x;
    const int tx = tid & 63;
    const int wv = tid >> 6;         // wave = local row 0..3

    __shared__ int color_s[HW];
    __shared__ int lab_s[HW];
    __shared__ int changed_s;
    __shared__ int root_s[MAXK];
    __shared__ int nroot_s;
    __shared__ int by0[MAXK], by1[MAXK], bx0[MAXK], bx1[MAXK];
    __shared__ int sy[MAXK], sx[MAXK], shh[MAXK], sww[MAXK], scol[MAXK], sval[MAXK];
    __shared__ __align__(16) float comb_s[4][COMB_LD];
    __shared__ __align__(16) float sn_s[DD];
    __shared__ float red_s[4];

    // ---------- load grid, init labels ----------
    for (int i = tid; i < HW; i += 256) {
        int c = grid[b * HW + i];
        color_s[i] = c;
        lab_s[i] = (c > 0) ? i : SENTV;
    }
    __syncthreads();

    // ---------- CCL: min-label propagation + path compression ----------
    // Monotone-decreasing labels; converges to the unique fixpoint
    // (min linear index per 4-connected same-color component) ==
    // reference's nbr_min + pointer-jump loop.
    for (;;) {
        if (tid == 0) changed_s = 0;
        __syncthreads();
        for (int i = tid; i < HW; i += 256) {
            int c = color_s[i];
            if (c <= 0) continue;
            int m = lab_s[i];
            int r = i / WWID;
            int cc = i - r * WWID;
            if (r > 0        && color_s[i - WWID] == c) m = min(m, lab_s[i - WWID]);
            if (r < HH - 1   && color_s[i + WWID] == c) m = min(m, lab_s[i + WWID]);
            if (cc > 0       && color_s[i - 1]    == c) m = min(m, lab_s[i - 1]);
            if (cc < WWID-1  && color_s[i + 1]    == c) m = min(m, lab_s[i + 1]);
            for (;;) { int p = lab_s[m]; if (p >= m) break; m = p; }
            if (m < lab_s[i]) { lab_s[i] = m; changed_s = 1; }
        }
        __syncthreads();
        int ch = changed_s;
        __syncthreads();
        if (!ch) break;
    }

    // ---------- first 16 roots in raster order (wave 0 ballot scan) ----------
    if (tid < 64) {
        int base = 0;
        for (int chk = 0; chk < 15; ++chk) {
            int cell = chk * 64 + tid;
            bool isr = (cell < HW) && (color_s[cell] > 0) && (lab_s[cell] == cell);
            unsigned long long mask = __ballot(isr);
            int rank = base + __popcll(mask & ((1ull << tid) - 1ull));
            if (isr && rank < MAXK) root_s[rank] = cell;
            base += __popcll(mask);
        }
        if (tid == 0) nroot_s = base;
        if (tid < MAXK) { by0[tid] = HH; by1[tid] = -1; bx0[tid] = WWID; bx1[tid] = -1; }
    }
    __syncthreads();

    // ---------- bboxes via LDS atomics ----------
    const int nval = min(nroot_s, MAXK);
    for (int i = tid; i < HW; i += 256) {
        if (color_s[i] <= 0) continue;
        int L = lab_s[i];
        int s = -1;
        for (int k = 0; k < nval; ++k) if (root_s[k] == L) { s = k; break; }
        if (s >= 0) {
            int r = i / WWID;
            int cc = i - r * WWID;
            atomicMin(&by0[s], r); atomicMax(&by1[s], r);
            atomicMin(&bx0[s], cc); atomicMax(&bx1[s], cc);
        }
    }
    __syncthreads();
    if (tid < MAXK) {
        int v = (tid < nval) ? 1 : 0;
        sval[tid] = v;
        if (v) {
            sy[tid] = by0[tid]; sx[tid] = bx0[tid];
            shh[tid] = by1[tid] + 1 - by0[tid];
            sww[tid] = bx1[tid] + 1 - bx0[tid];
            scol[tid] = color_s[root_s[tid]];
        } else { sy[tid] = 0; sx[tid] = 0; shh[tid] = 1; sww[tid] = 1; scol[tid] = 0; }
    }

    // ---------- structure mean + L2-normalize -> sn_s ----------
    {
        float s = 0.f;
        const float* sr = structure_rep + (size_t)b * KS * DD + tid;
        for (int j = 0; j < KS; ++j) s += sr[(size_t)j * DD];
        s *= (1.0f / (float)KS);
        float ss = s * s;
        #pragma unroll
        for (int off = 32; off > 0; off >>= 1) ss += __shfl_xor(ss, off);
        if (tx == 0) red_s[wv] = ss;
        __syncthreads();   // red_s ready; also publishes sval/bbox arrays
        float nrm = sqrtf(red_s[0] + red_s[1] + red_s[2] + red_s[3]);
        sn_s[tid] = s / fmaxf(nrm, 1e-8f);
    }

    // ---------- bbox pooling: wave wv owns slot 4q+wv, lanes = float4 dims ----
    {
        const int slot = q * 4 + wv;
        const int d0 = tx * 4;
        float4 pv = make_float4(0.f, 0.f, 0.f, 0.f);
        if (sval[slot]) {
            int y = sy[slot], x = sx[slot], h = shh[slot], w = sww[slot];
            float4 sum = make_float4(0.f, 0.f, 0.f, 0.f);
            for (int yy = y; yy < y + h; ++yy) {
                const float* p = grid_emb + ((size_t)(b * HH + yy) * WWID + x) * DD + d0;
                for (int xx = 0; xx < w; ++xx) {
                    float4 v = *(const float4*)(p + (size_t)xx * DD);
                    sum.x += v.x; sum.y += v.y; sum.z += v.z; sum.w += v.w;
                }
            }
            float inv = 1.0f / (float)(h * w);
            pv.x = sum.x * inv; pv.y = sum.y * inv; pv.z = sum.z * inv; pv.w = sum.w * inv;
        }
        *(float4*)(&comb_s[wv][d0]) = pv;
        if (tx < 5) {
            float f = 0.f;
            if (sval[slot]) {
                switch (tx) {
                    case 0: f = (float)scol[slot] / 9.0f;  break;
                    case 1: f = (float)sx[slot]  / 30.0f;  break;
                    case 2: f = (float)sy[slot]  / 30.0f;  break;
                    case 3: f = (float)sww[slot] / 30.0f;  break;
                    case 4: f = (float)shh[slot] / 30.0f;  break;
                }
            }
            comb_s[wv][256 + tx] = f;
        }
    }
    __syncthreads();   // comb_s + sn_s visible

    // ================= wave-local MLP pipeline (no more barriers) ==========
    const int slot = q * 4 + wv;
    const int c0 = tx * 4;

    // GEMM1: hdn = gelu(comb @ W1 + b1), K = 261
    float4 areg = *(const float4*)(&comb_s[wv][c0]);   // chunk tx of A-row
    float4 acc = gemm_row_k256(areg, W1, c0);
    {   // tail f = 256..260 (bbox feats), broadcast from LDS
        #pragma unroll
        for (int j = 0; j < 5; ++j) {
            float a = comb_s[wv][256 + j];
            float4 bt = *(const float4*)(W1 + (size_t)(256 + j) * DD + c0);
            acc.x += a * bt.x; acc.y += a * bt.y; acc.z += a * bt.z; acc.w += a * bt.w;
        }
        float4 b1v = *(const float4*)(b1 + c0);
        areg.x = gelu_exact(acc.x + b1v.x);
        areg.y = gelu_exact(acc.y + b1v.y);
        areg.z = gelu_exact(acc.z + b1v.z);
        areg.w = gelu_exact(acc.w + b1v.w);
    }

    // GEMM2: obj = (hdn @ W2 + b2) * valid   (hdn chunk == areg, stays in regs)
    acc = gemm_row_k256(areg, W2, c0);
    {
        float4 b2v = *(const float4*)(b2 + c0);
        float vm = sval[slot] ? 1.f : 0.f;
        areg.x = (acc.x + b2v.x) * vm;
        areg.y = (acc.y + b2v.y) * vm;
        areg.z = (acc.z + b2v.z) * vm;
        areg.w = (acc.w + b2v.w) * vm;
    }

    // ortho rejection: co = (obj - (obj.sn) sn) * ortho_scale
    {
        float4 snv = *(const float4*)(sn_s + c0);
        float p = areg.x * snv.x + areg.y * snv.y + areg.z * snv.z + areg.w * snv.w;
        #pragma unroll
        for (int off = 32; off > 0; off >>= 1) p += __shfl_xor(p, off);
        float ortho = ortho_scale[0];
        areg.x = (areg.x - p * snv.x) * ortho;
        areg.y = (areg.y - p * snv.y) * ortho;
        areg.z = (areg.z - p * snv.z) * ortho;
        areg.w = (areg.w - p * snv.w) * ortho;
    }

    // GEMM3: co @ Wp + bp, then LayerNorm
    acc = gemm_row_k256(areg, Wp, c0);
    {
        float4 bpv = *(const float4*)(bp + c0);
        float v0 = acc.x + bpv.x;
        float v1 = acc.y + bpv.y;
        float v2 = acc.z + bpv.z;
        float v3 = acc.w + bpv.w;
        float sm = v0 + v1 + v2 + v3;
        float sq = v0 * v0 + v1 * v1 + v2 * v2 + v3 * v3;
        #pragma unroll
        for (int off = 32; off > 0; off >>= 1) {
            sm += __shfl_xor(sm, off);
            sq += __shfl_xor(sq, off);
        }
        float mu   = sm * (1.0f / 256.0f);
        float var  = fmaxf(sq * (1.0f / 256.0f) - mu * mu, 0.0f);
        float rstd = 1.0f / sqrtf(var + 1e-5f);
        float4 gv = *(const float4*)(gvec + c0);
        float4 bv = *(const float4*)(bvec + c0);
        float4 o;
        o.x = (v0 - mu) * rstd * gv.x + bv.x;
        o.y = (v1 - mu) * rstd * gv.y + bv.y;
        o.z = (v2 - mu) * rstd * gv.z + bv.z;
        o.w = (v3 - mu) * rstd * gv.w + bv.w;
        *(float4*)(out + ((size_t)b * MAXK + slot) * DD + c0) = o;
    }
}

extern "C" void kernel_launch(void* const* d_in, const int* in_sizes, int n_in,
                              void* d_out, int out_size, void* d_ws, size_t ws_size,
                              hipStream_t stream) {
    const float* grid_emb = (const float*)d_in[0];
    const int*   grid     = (const int*)d_in[1];
    const float* srep     = (const float*)d_in[2];
    const float* W1v = (const float*)d_in[3];
    const float* b1v = (const float*)d_in[4];
    const float* W2v = (const float*)d_in[5];
    const float* b2v = (const float*)d_in[6];
    const float* Wpv = (const float*)d_in[7];
    const float* bpv = (const float*)d_in[8];
    const float* gv  = (const float*)d_in[9];
    const float* bv  = (const float*)d_in[10];
    const float* osv = (const float*)d_in[11];
    float* out = (float*)d_out;

    const int B  = in_sizes[1] / HW;
    const int KS = in_sizes[2] / (B * DD);

    hipLaunchKernelGGL(ccce_fused, dim3(B * 4), dim3(256), 0, stream,
                       grid_emb, grid, srep, W1v, b1v, W2v, b2v, Wpv, bpv,
                       gv, bv, osv, out, KS);
}

// Round 3
// 39.189 us; speedup vs baseline: 1.8741x; 1.7160x over previous
//
#include <hip/hip_runtime.h>
#include <math.h>

#define HH 30
#define WWID 30
#define HW 900
#define SENTV 900
#define DD 256
#define MAXK 16
#define A_LD 264

__device__ __forceinline__ float gelu_exact(float x) {
    return 0.5f * x * (1.0f + erff(x * 0.70710678118654752440f));
}

// Split-K GEMM partial phase: wave wv handles k in [32wv, 32wv+32).
// Each thread: 8 rows x 4 cols. Waves 0-3 write partials, waves 4-7 fold in.
// Ends with part_s[0..3] holding the 4 remaining partials + barrier.
#define GEMM_PHASE(Asrc, Wm)                                                  \
    {                                                                         \
        const int kbase = wv * 32;                                            \
        float acc[8][4];                                                      \
        _Pragma("unroll")                                                     \
        for (int r = 0; r < 8; ++r) {                                         \
            acc[r][0] = 0.f; acc[r][1] = 0.f; acc[r][2] = 0.f; acc[r][3] = 0.f;\
        }                                                                     \
        _Pragma("unroll 8")                                                   \
        for (int kk = 0; kk < 32; ++kk) {                                     \
            const int k = kbase + kk;                                         \
            float4 wrow = *(const float4*)((Wm) + (size_t)k * DD + c0);       \
            _Pragma("unroll")                                                 \
            for (int r = 0; r < 8; ++r) {                                     \
                float a = Asrc[r][k];                                         \
                acc[r][0] += a * wrow.x;                                      \
                acc[r][1] += a * wrow.y;                                      \
                acc[r][2] += a * wrow.z;                                      \
                acc[r][3] += a * wrow.w;                                      \
            }                                                                 \
        }                                                                     \
        if (wv < 4) {                                                         \
            _Pragma("unroll")                                                 \
            for (int r = 0; r < 8; ++r)                                       \
                *(float4*)(&part_s[wv][r][c0]) =                              \
                    make_float4(acc[r][0], acc[r][1], acc[r][2], acc[r][3]);  \
        }                                                                     \
        __syncthreads();                                                      \
        if (wv >= 4) {                                                        \
            _Pragma("unroll")                                                 \
            for (int r = 0; r < 8; ++r) {                                     \
                float4 p = *(const float4*)(&part_s[wv - 4][r][c0]);          \
                p.x += acc[r][0]; p.y += acc[r][1];                           \
                p.z += acc[r][2]; p.w += acc[r][3];                           \
                *(float4*)(&part_s[wv - 4][r][c0]) = p;                       \
            }                                                                 \
        }                                                                     \
        __syncthreads();                                                      \
    }

// Sum the 4 remaining partials for (row=wv, cols c0..c0+3).
#define REDUCE4(sv)                                                           \
    float4 sv = *(const float4*)(&part_s[0][wv][c0]);                         \
    {                                                                         \
        _Pragma("unroll")                                                     \
        for (int w = 1; w < 4; ++w) {                                         \
            float4 p = *(const float4*)(&part_s[w][wv][c0]);                  \
            sv.x += p.x; sv.y += p.y; sv.z += p.z; sv.w += p.w;               \
        }                                                                     \
    }

__global__ __launch_bounds__(512) void ccce_fused(
    const float* __restrict__ grid_emb,
    const int* __restrict__ grid,
    const float* __restrict__ structure_rep,
    const float* __restrict__ W1, const float* __restrict__ b1,
    const float* __restrict__ W2, const float* __restrict__ b2,
    const float* __restrict__ Wp, const float* __restrict__ bp,
    const float* __restrict__ gvec, const float* __restrict__ bvec,
    const float* __restrict__ ortho_scale,
    float* __restrict__ out, int KS)
{
    const int b   = blockIdx.x >> 1;   // batch
    const int h8  = blockIdx.x & 1;    // row-half: slots 8*h8 .. 8*h8+7
    const int tid = threadIdx.x;
    const int tx  = tid & 63;
    const int wv  = tid >> 6;          // wave 0..7
    const int c0  = tx * 4;            // 4 cols per lane

    __shared__ int color_s[HW];
    __shared__ int lab_s[HW];
    __shared__ int changed_s;
    __shared__ int root_s[MAXK];
    __shared__ int nroot_s;
    __shared__ int by0[MAXK], by1[MAXK], bx0[MAXK], bx1[MAXK];
    __shared__ int sy[MAXK], sx[MAXK], shh[MAXK], sww[MAXK], scol[MAXK], sval[MAXK];
    __shared__ __align__(16) float A1_s[8][A_LD];     // comb, later co
    __shared__ __align__(16) float A2_s[8][A_LD];     // hdn
    __shared__ __align__(16) float part_s[4][8][DD];  // 32 KB split-K partials
    __shared__ __align__(16) float sn_s[DD];
    __shared__ float red_s[4];

    // ---------- load grid (int4), init labels ----------
    {
        const int4* gp = (const int4*)(grid + (size_t)b * HW);
        if (tid < 225) {
            int4 g = gp[tid];
            int i = tid * 4;
            color_s[i + 0] = g.x; lab_s[i + 0] = (g.x > 0) ? (i + 0) : SENTV;
            color_s[i + 1] = g.y; lab_s[i + 1] = (g.y > 0) ? (i + 1) : SENTV;
            color_s[i + 2] = g.z; lab_s[i + 2] = (g.z > 0) ? (i + 2) : SENTV;
            color_s[i + 3] = g.w; lab_s[i + 3] = (g.w > 0) ? (i + 3) : SENTV;
        }
    }
    __syncthreads();

    // ---------- CCL: min-label propagation + path compression ----------
    for (;;) {
        if (tid == 0) changed_s = 0;
        __syncthreads();
        for (int i = tid; i < HW; i += 512) {
            int c = color_s[i];
            if (c <= 0) continue;
            int m = lab_s[i];
            int r = i / WWID;
            int cc = i - r * WWID;
            if (r > 0        && color_s[i - WWID] == c) m = min(m, lab_s[i - WWID]);
            if (r < HH - 1   && color_s[i + WWID] == c) m = min(m, lab_s[i + WWID]);
            if (cc > 0       && color_s[i - 1]    == c) m = min(m, lab_s[i - 1]);
            if (cc < WWID-1  && color_s[i + 1]    == c) m = min(m, lab_s[i + 1]);
            for (;;) { int p = lab_s[m]; if (p >= m) break; m = p; }
            if (m < lab_s[i]) { lab_s[i] = m; changed_s = 1; }
        }
        __syncthreads();
        int ch = changed_s;
        __syncthreads();
        if (!ch) break;
    }

    // ---------- first 16 roots in raster order (wave 0 ballot scan) ----------
    if (tid < 64) {
        int base = 0;
        for (int chk = 0; chk < 15; ++chk) {
            int cell = chk * 64 + tid;
            bool isr = (cell < HW) && (color_s[cell] > 0) && (lab_s[cell] == cell);
            unsigned long long mask = __ballot(isr);
            int rank = base + __popcll(mask & ((1ull << tid) - 1ull));
            if (isr && rank < MAXK) root_s[rank] = cell;
            base += __popcll(mask);
        }
        if (tid == 0) nroot_s = base;
        if (tid < MAXK) { by0[tid] = HH; by1[tid] = -1; bx0[tid] = WWID; bx1[tid] = -1; }
    }
    __syncthreads();

    // ---------- bboxes via LDS atomics ----------
    const int nval = min(nroot_s, MAXK);
    for (int i = tid; i < HW; i += 512) {
        if (color_s[i] <= 0) continue;
        int L = lab_s[i];
        int s = -1;
        for (int k = 0; k < nval; ++k) if (root_s[k] == L) { s = k; break; }
        if (s >= 0) {
            int r = i / WWID;
            int cc = i - r * WWID;
            atomicMin(&by0[s], r); atomicMax(&by1[s], r);
            atomicMin(&bx0[s], cc); atomicMax(&bx1[s], cc);
        }
    }
    __syncthreads();

    // ---------- slot meta + structure-mean partial ----------
    if (tid < MAXK) {
        int v = (tid < nval) ? 1 : 0;
        sval[tid] = v;
        if (v) {
            sy[tid] = by0[tid]; sx[tid] = bx0[tid];
            shh[tid] = by1[tid] + 1 - by0[tid];
            sww[tid] = bx1[tid] + 1 - bx0[tid];
            scol[tid] = color_s[root_s[tid]];
        } else { sy[tid] = 0; sx[tid] = 0; shh[tid] = 1; sww[tid] = 1; scol[tid] = 0; }
    }
    float s_mean = 0.f;
    if (tid < DD) {
        const float* sr = structure_rep + (size_t)b * KS * DD + tid;
        for (int j = 0; j < KS; ++j) s_mean += sr[(size_t)j * DD];
        s_mean *= (1.0f / (float)KS);
    }
    {
        float ss = s_mean * s_mean;
        #pragma unroll
        for (int off = 32; off > 0; off >>= 1) ss += __shfl_xor(ss, off);
        if (tx == 0 && wv < 4) red_s[wv] = ss;
    }
    __syncthreads();   // slot meta + red_s ready

    // ---------- sn + bbox pooling (wave wv pools slot 8*h8+wv) ----------
    if (tid < DD) {
        float nrm = sqrtf(red_s[0] + red_s[1] + red_s[2] + red_s[3]);
        sn_s[tid] = s_mean / fmaxf(nrm, 1e-8f);
    }
    {
        const int slot = h8 * 8 + wv;
        float4 pv = make_float4(0.f, 0.f, 0.f, 0.f);
        if (sval[slot]) {
            int y = sy[slot], x = sx[slot], h = shh[slot], w = sww[slot];
            float4 sum = make_float4(0.f, 0.f, 0.f, 0.f);
            for (int yy = y; yy < y + h; ++yy) {
                const float* p = grid_emb + ((size_t)(b * HH + yy) * WWID + x) * DD + c0;
                for (int xx = 0; xx < w; ++xx) {
                    float4 v = *(const float4*)(p + (size_t)xx * DD);
                    sum.x += v.x; sum.y += v.y; sum.z += v.z; sum.w += v.w;
                }
            }
            float inv = 1.0f / (float)(h * w);
            pv.x = sum.x * inv; pv.y = sum.y * inv; pv.z = sum.z * inv; pv.w = sum.w * inv;
        }
        *(float4*)(&A1_s[wv][c0]) = pv;
        if (tx < 5) {
            const int slot2 = h8 * 8 + wv;
            float f = 0.f;
            if (sval[slot2]) {
                switch (tx) {
                    case 0: f = (float)scol[slot2] / 9.0f;  break;
                    case 1: f = (float)sx[slot2]  / 30.0f;  break;
                    case 2: f = (float)sy[slot2]  / 30.0f;  break;
                    case 3: f = (float)sww[slot2] / 30.0f;  break;
                    case 4: f = (float)shh[slot2] / 30.0f;  break;
                }
            }
            A1_s[wv][256 + tx] = f;
        }
    }
    __syncthreads();   // A1 (comb) + sn ready

    // ================= GEMM1: hdn = gelu(comb @ W1 + b1) =================
    GEMM_PHASE(A1_s, W1);
    {
        REDUCE4(s);
        // fold in the 5 bbox-feature k's (256..260)
        #pragma unroll
        for (int j = 0; j < 5; ++j) {
            float a = A1_s[wv][256 + j];
            float4 wrow = *(const float4*)(W1 + (size_t)(256 + j) * DD + c0);
            s.x += a * wrow.x; s.y += a * wrow.y; s.z += a * wrow.z; s.w += a * wrow.w;
        }
        float4 bb = *(const float4*)(b1 + c0);
        float4 hv;
        hv.x = gelu_exact(s.x + bb.x);
        hv.y = gelu_exact(s.y + bb.y);
        hv.z = gelu_exact(s.z + bb.z);
        hv.w = gelu_exact(s.w + bb.w);
        *(float4*)(&A2_s[wv][c0]) = hv;
    }
    __syncthreads();

    // ================= GEMM2: obj = (hdn @ W2 + b2) * valid; ortho ========
    GEMM_PHASE(A2_s, W2);
    {
        REDUCE4(s);
        float4 bb = *(const float4*)(b2 + c0);
        float vm = sval[h8 * 8 + wv] ? 1.f : 0.f;
        float o0 = (s.x + bb.x) * vm;
        float o1 = (s.y + bb.y) * vm;
        float o2 = (s.z + bb.z) * vm;
        float o3 = (s.w + bb.w) * vm;
        float4 snv = *(const float4*)(sn_s + c0);
        float p = o0 * snv.x + o1 * snv.y + o2 * snv.z + o3 * snv.w;
        #pragma unroll
        for (int off = 32; off > 0; off >>= 1) p += __shfl_xor(p, off);
        float osc = ortho_scale[0];
        float4 co;
        co.x = (o0 - p * snv.x) * osc;
        co.y = (o1 - p * snv.y) * osc;
        co.z = (o2 - p * snv.z) * osc;
        co.w = (o3 - p * snv.w) * osc;
        *(float4*)(&A1_s[wv][c0]) = co;   // A1 rows 0..255 now hold co
    }
    __syncthreads();

    // ================= GEMM3: co @ Wp + bp, LayerNorm =====================
    GEMM_PHASE(A1_s, Wp);
    {
        REDUCE4(s);
        float4 bb = *(const float4*)(bp + c0);
        float v0 = s.x + bb.x;
        float v1 = s.y + bb.y;
        float v2 = s.z + bb.z;
        float v3 = s.w + bb.w;
        float sm = v0 + v1 + v2 + v3;
        float sq = v0 * v0 + v1 * v1 + v2 * v2 + v3 * v3;
        #pragma unroll
        for (int off = 32; off > 0; off >>= 1) {
            sm += __shfl_xor(sm, off);
            sq += __shfl_xor(sq, off);
        }
        float mu   = sm * (1.0f / 256.0f);
        float var  = fmaxf(sq * (1.0f / 256.0f) - mu * mu, 0.0f);
        float rstd = 1.0f / sqrtf(var + 1e-5f);
        float4 gv = *(const float4*)(gvec + c0);
        float4 bv = *(const float4*)(bvec + c0);
        float4 o;
        o.x = (v0 - mu) * rstd * gv.x + bv.x;
        o.y = (v1 - mu) * rstd * gv.y + bv.y;
        o.z = (v2 - mu) * rstd * gv.z + bv.z;
        o.w = (v3 - mu) * rstd * gv.w + bv.w;
        *(float4*)(out + ((size_t)b * MAXK + h8 * 8 + wv) * DD + c0) = o;
    }
}

extern "C" void kernel_launch(void* const* d_in, const int* in_sizes, int n_in,
                              void* d_out, int out_size, void* d_ws, size_t ws_size,
                              hipStream_t stream) {
    const float* grid_emb = (const float*)d_in[0];
    const int*   grid     = (const int*)d_in[1];
    const float* srep     = (const float*)d_in[2];
    const float* W1v = (const float*)d_in[3];
    const float* b1v = (const float*)d_in[4];
    const float* W2v = (const float*)d_in[5];
    const float* b2v = (const float*)d_in[6];
    const float* Wpv = (const float*)d_in[7];
    const float* bpv = (const float*)d_in[8];
    const float* gv  = (const float*)d_in[9];
    const float* bv  = (const float*)d_in[10];
    const float* osv = (const float*)d_in[11];
    float* out = (float*)d_out;

    const int B  = in_sizes[1] / HW;
    const int KS = in_sizes[2] / (B * DD);

    hipLaunchKernelGGL(ccce_fused, dim3(B * 2), dim3(512), 0, stream,
                       grid_emb, grid, srep, W1v, b1v, W2v, b2v, Wpv, bpv,
                       gv, bv, osv, out, KS);
}

// Round 4
// 32.292 us; speedup vs baseline: 2.2744x; 1.2136x over previous
//
#include <hip/hip_runtime.h>
#include <math.h>

#define HH 30
#define WWID 30
#define HW 900
#define SENTV 900
#define DD 256
#define MAXK 16
#define A_LD 264

#define COMP(v, jj) ((jj) == 0 ? (v).x : (jj) == 1 ? (v).y : (jj) == 2 ? (v).z : (v).w)

__device__ __forceinline__ float gelu_exact(float x) {
    return 0.5f * x * (1.0f + erff(x * 0.70710678118654752440f));
}

// Split-K GEMM phase: wave wv owns k in [32wv, 32wv+32), 8 rows x 4 cols/thread.
// Software-pipelined: chunk c+1's 8 weight float4s issued before chunk c's FMAs.
// Ends with part[0..3] holding 4 remaining partials; two barriers inside.
__device__ __forceinline__ void gemm_phase(
    const float (* __restrict__ Asrc)[A_LD],
    const float* __restrict__ Wm,
    float (* __restrict__ part)[8][DD],
    int wv, int c0)
{
    const int kbase = wv * 32;
    float acc[8][4];
    #pragma unroll
    for (int r = 0; r < 8; ++r) { acc[r][0] = 0.f; acc[r][1] = 0.f; acc[r][2] = 0.f; acc[r][3] = 0.f; }

    const float* wp = Wm + (size_t)kbase * DD + c0;
    float4 wc[8], wn[8];
    #pragma unroll
    for (int j = 0; j < 8; ++j) wc[j] = *(const float4*)(wp + (size_t)j * DD);

    #pragma unroll
    for (int ch = 0; ch < 4; ++ch) {
        if (ch < 3) {   // prefetch next weight chunk (in flight across this chunk's FMAs)
            const float* wpn = wp + (size_t)((ch + 1) * 8) * DD;
            #pragma unroll
            for (int j = 0; j < 8; ++j) wn[j] = *(const float4*)(wpn + (size_t)j * DD);
        }
        // A for this chunk: 8 rows x 8 k, wave-uniform broadcast b128 reads
        float4 aA[8], aB[8];
        #pragma unroll
        for (int r = 0; r < 8; ++r) {
            aA[r] = *(const float4*)(&Asrc[r][kbase + ch * 8]);
            aB[r] = *(const float4*)(&Asrc[r][kbase + ch * 8 + 4]);
        }
        #pragma unroll
        for (int j = 0; j < 4; ++j) {
            #pragma unroll
            for (int r = 0; r < 8; ++r) {
                float av = COMP(aA[r], j);
                acc[r][0] += av * wc[j].x;
                acc[r][1] += av * wc[j].y;
                acc[r][2] += av * wc[j].z;
                acc[r][3] += av * wc[j].w;
            }
        }
        #pragma unroll
        for (int j = 0; j < 4; ++j) {
            #pragma unroll
            for (int r = 0; r < 8; ++r) {
                float av = COMP(aB[r], j);
                acc[r][0] += av * wc[4 + j].x;
                acc[r][1] += av * wc[4 + j].y;
                acc[r][2] += av * wc[4 + j].z;
                acc[r][3] += av * wc[4 + j].w;
            }
        }
        if (ch < 3) {
            #pragma unroll
            for (int j = 0; j < 8; ++j) wc[j] = wn[j];
        }
    }

    if (wv < 4) {
        #pragma unroll
        for (int r = 0; r < 8; ++r)
            *(float4*)(&part[wv][r][c0]) = make_float4(acc[r][0], acc[r][1], acc[r][2], acc[r][3]);
    }
    __syncthreads();
    if (wv >= 4) {
        #pragma unroll
        for (int r = 0; r < 8; ++r) {
            float4 p = *(const float4*)(&part[wv - 4][r][c0]);
            p.x += acc[r][0]; p.y += acc[r][1]; p.z += acc[r][2]; p.w += acc[r][3];
            *(float4*)(&part[wv - 4][r][c0]) = p;
        }
    }
    __syncthreads();
}

__global__ __launch_bounds__(512, 2) void ccce_fused(
    const float* __restrict__ grid_emb,
    const int* __restrict__ grid,
    const float* __restrict__ structure_rep,
    const float* __restrict__ W1, const float* __restrict__ b1,
    const float* __restrict__ W2, const float* __restrict__ b2,
    const float* __restrict__ Wp, const float* __restrict__ bp,
    const float* __restrict__ gvec, const float* __restrict__ bvec,
    const float* __restrict__ ortho_scale,
    float* __restrict__ out, int KS)
{
    const int b   = blockIdx.x >> 1;   // batch
    const int h8  = blockIdx.x & 1;    // row-half: slots 8*h8 .. 8*h8+7
    const int tid = threadIdx.x;
    const int tx  = tid & 63;
    const int wv  = tid >> 6;          // wave 0..7
    const int c0  = tx * 4;            // 4 cols per lane

    __shared__ int color_s[HW];
    __shared__ int lab_s[HW];
    __shared__ int changed_s;
    __shared__ int root_s[MAXK];
    __shared__ int nroot_s;
    __shared__ int by0[MAXK], by1[MAXK], bx0[MAXK], bx1[MAXK];
    __shared__ int sy[MAXK], sx[MAXK], shh[MAXK], sww[MAXK], scol[MAXK], sval[MAXK];
    __shared__ __align__(16) float A1_s[8][A_LD];     // comb, later co
    __shared__ __align__(16) float A2_s[8][A_LD];     // hdn
    __shared__ __align__(16) float part_s[4][8][DD];  // 32 KB split-K partials
    __shared__ __align__(16) float sn_s[DD];
    __shared__ float red_s[4];

    // ---------- load grid (int4), init labels ----------
    {
        const int4* gp = (const int4*)(grid + (size_t)b * HW);
        if (tid < 225) {
            int4 g = gp[tid];
            int i = tid * 4;
            color_s[i + 0] = g.x; lab_s[i + 0] = (g.x > 0) ? (i + 0) : SENTV;
            color_s[i + 1] = g.y; lab_s[i + 1] = (g.y > 0) ? (i + 1) : SENTV;
            color_s[i + 2] = g.z; lab_s[i + 2] = (g.z > 0) ? (i + 2) : SENTV;
            color_s[i + 3] = g.w; lab_s[i + 3] = (g.w > 0) ? (i + 3) : SENTV;
        }
    }
    __syncthreads();

    // ---------- CCL: min-label propagation + path compression ----------
    // Monotone-decreasing; converges to min-linear-index-per-component.
    // Convergence test only every 2nd sweep (extra sweeps are idempotent).
    for (;;) {
        if (tid == 0) changed_s = 0;
        // sweep 1 (no check)
        for (int i = tid; i < HW; i += 512) {
            int c = color_s[i];
            if (c <= 0) continue;
            int m = lab_s[i];
            int r = i / WWID;
            int cc = i - r * WWID;
            if (r > 0        && color_s[i - WWID] == c) m = min(m, lab_s[i - WWID]);
            if (r < HH - 1   && color_s[i + WWID] == c) m = min(m, lab_s[i + WWID]);
            if (cc > 0       && color_s[i - 1]    == c) m = min(m, lab_s[i - 1]);
            if (cc < WWID-1  && color_s[i + 1]    == c) m = min(m, lab_s[i + 1]);
            for (;;) { int p = lab_s[m]; if (p >= m) break; m = p; }
            if (m < lab_s[i]) lab_s[i] = m;
        }
        __syncthreads();
        // sweep 2 (with check)
        for (int i = tid; i < HW; i += 512) {
            int c = color_s[i];
            if (c <= 0) continue;
            int m = lab_s[i];
            int r = i / WWID;
            int cc = i - r * WWID;
            if (r > 0        && color_s[i - WWID] == c) m = min(m, lab_s[i - WWID]);
            if (r < HH - 1   && color_s[i + WWID] == c) m = min(m, lab_s[i + WWID]);
            if (cc > 0       && color_s[i - 1]    == c) m = min(m, lab_s[i - 1]);
            if (cc < WWID-1  && color_s[i + 1]    == c) m = min(m, lab_s[i + 1]);
            for (;;) { int p = lab_s[m]; if (p >= m) break; m = p; }
            if (m < lab_s[i]) { lab_s[i] = m; changed_s = 1; }
        }
        __syncthreads();
        int ch = changed_s;
        __syncthreads();
        if (!ch) break;
    }

    // ---------- first 16 roots in raster order (wave 0 ballot scan) ----------
    if (tid < 64) {
        int base = 0;
        for (int chk = 0; chk < 15; ++chk) {
            int cell = chk * 64 + tid;
            bool isr = (cell < HW) && (color_s[cell] > 0) && (lab_s[cell] == cell);
            unsigned long long mask = __ballot(isr);
            int rank = base + __popcll(mask & ((1ull << tid) - 1ull));
            if (isr && rank < MAXK) root_s[rank] = cell;
            base += __popcll(mask);
        }
        if (tid == 0) nroot_s = base;
        if (tid < MAXK) { by0[tid] = HH; by1[tid] = -1; bx0[tid] = WWID; bx1[tid] = -1; }
    }
    __syncthreads();

    // ---------- bboxes via LDS atomics ----------
    const int nval = min(nroot_s, MAXK);
    for (int i = tid; i < HW; i += 512) {
        if (color_s[i] <= 0) continue;
        int L = lab_s[i];
        int s = -1;
        for (int k = 0; k < nval; ++k) if (root_s[k] == L) { s = k; break; }
        if (s >= 0) {
            int r = i / WWID;
            int cc = i - r * WWID;
            atomicMin(&by0[s], r); atomicMax(&by1[s], r);
            atomicMin(&bx0[s], cc); atomicMax(&bx1[s], cc);
        }
    }
    __syncthreads();

    // ---------- slot meta + structure-mean partial ----------
    if (tid < MAXK) {
        int v = (tid < nval) ? 1 : 0;
        sval[tid] = v;
        if (v) {
            sy[tid] = by0[tid]; sx[tid] = bx0[tid];
            shh[tid] = by1[tid] + 1 - by0[tid];
            sww[tid] = bx1[tid] + 1 - bx0[tid];
            scol[tid] = color_s[root_s[tid]];
        } else { sy[tid] = 0; sx[tid] = 0; shh[tid] = 1; sww[tid] = 1; scol[tid] = 0; }
    }
    float s_mean = 0.f;
    if (tid < DD) {
        const float* sr = structure_rep + (size_t)b * KS * DD + tid;
        for (int j = 0; j < KS; ++j) s_mean += sr[(size_t)j * DD];
        s_mean *= (1.0f / (float)KS);
    }
    {
        float ss = s_mean * s_mean;
        #pragma unroll
        for (int off = 32; off > 0; off >>= 1) ss += __shfl_xor(ss, off);
        if (tx == 0 && wv < 4) red_s[wv] = ss;
    }
    __syncthreads();   // slot meta + red_s ready

    // ---------- sn + bbox pooling (wave wv pools slot 8*h8+wv) ----------
    if (tid < DD) {
        float nrm = sqrtf(red_s[0] + red_s[1] + red_s[2] + red_s[3]);
        sn_s[tid] = s_mean / fmaxf(nrm, 1e-8f);
    }
    {
        const int slot = h8 * 8 + wv;
        float4 pv = make_float4(0.f, 0.f, 0.f, 0.f);
        if (sval[slot]) {
            int y = sy[slot], x = sx[slot], h = shh[slot], w = sww[slot];
            float4 sum = make_float4(0.f, 0.f, 0.f, 0.f);
            for (int yy = y; yy < y + h; ++yy) {
                const float* p = grid_emb + ((size_t)(b * HH + yy) * WWID + x) * DD + c0;
                for (int xx = 0; xx < w; ++xx) {
                    float4 v = *(const float4*)(p + (size_t)xx * DD);
                    sum.x += v.x; sum.y += v.y; sum.z += v.z; sum.w += v.w;
                }
            }
            float inv = 1.0f / (float)(h * w);
            pv.x = sum.x * inv; pv.y = sum.y * inv; pv.z = sum.z * inv; pv.w = sum.w * inv;
        }
        *(float4*)(&A1_s[wv][c0]) = pv;
        if (tx < 5) {
            const int slot2 = h8 * 8 + wv;
            float f = 0.f;
            if (sval[slot2]) {
                switch (tx) {
                    case 0: f = (float)scol[slot2] / 9.0f;  break;
                    case 1: f = (float)sx[slot2]  / 30.0f;  break;
                    case 2: f = (float)sy[slot2]  / 30.0f;  break;
                    case 3: f = (float)sww[slot2] / 30.0f;  break;
                    case 4: f = (float)shh[slot2] / 30.0f;  break;
                }
            }
            A1_s[wv][256 + tx] = f;
        }
    }
    __syncthreads();   // A1 (comb) + sn ready

    // ================= GEMM1: hdn = gelu(comb @ W1 + b1) =================
    gemm_phase(A1_s, W1, part_s, wv, c0);
    {
        float4 s = *(const float4*)(&part_s[0][wv][c0]);
        #pragma unroll
        for (int w = 1; w < 4; ++w) {
            float4 p = *(const float4*)(&part_s[w][wv][c0]);
            s.x += p.x; s.y += p.y; s.z += p.z; s.w += p.w;
        }
        #pragma unroll
        for (int j = 0; j < 5; ++j) {   // bbox-feature k's 256..260
            float a = A1_s[wv][256 + j];
            float4 wrow = *(const float4*)(W1 + (size_t)(256 + j) * DD + c0);
            s.x += a * wrow.x; s.y += a * wrow.y; s.z += a * wrow.z; s.w += a * wrow.w;
        }
        float4 bb = *(const float4*)(b1 + c0);
        float4 hv;
        hv.x = gelu_exact(s.x + bb.x);
        hv.y = gelu_exact(s.y + bb.y);
        hv.z = gelu_exact(s.z + bb.z);
        hv.w = gelu_exact(s.w + bb.w);
        *(float4*)(&A2_s[wv][c0]) = hv;
    }
    __syncthreads();

    // ================= GEMM2: obj = (hdn @ W2 + b2) * valid; ortho ========
    gemm_phase(A2_s, W2, part_s, wv, c0);
    {
        float4 s = *(const float4*)(&part_s[0][wv][c0]);
        #pragma unroll
        for (int w = 1; w < 4; ++w) {
            float4 p = *(const float4*)(&part_s[w][wv][c0]);
            s.x += p.x; s.y += p.y; s.z += p.z; s.w += p.w;
        }
        float4 bb = *(const float4*)(b2 + c0);
        float vm = sval[h8 * 8 + wv] ? 1.f : 0.f;
        float o0 = (s.x + bb.x) * vm;
        float o1 = (s.y + bb.y) * vm;
        float o2 = (s.z + bb.z) * vm;
        float o3 = (s.w + bb.w) * vm;
        float4 snv = *(const float4*)(sn_s + c0);
        float p = o0 * snv.x + o1 * snv.y + o2 * snv.z + o3 * snv.w;
        #pragma unroll
        for (int off = 32; off > 0; off >>= 1) p += __shfl_xor(p, off);
        float osc = ortho_scale[0];
        float4 co;
        co.x = (o0 - p * snv.x) * osc;
        co.y = (o1 - p * snv.y) * osc;
        co.z = (o2 - p * snv.z) * osc;
        co.w = (o3 - p * snv.w) * osc;
        *(float4*)(&A1_s[wv][c0]) = co;   // A1 rows now hold co
    }
    __syncthreads();

    // ================= GEMM3: co @ Wp + bp, LayerNorm =====================
    gemm_phase(A1_s, Wp, part_s, wv, c0);
    {
        float4 s = *(const float4*)(&part_s[0][wv][c0]);
        #pragma unroll
        for (int w = 1; w < 4; ++w) {
            float4 p = *(const float4*)(&part_s[w][wv][c0]);
            s.x += p.x; s.y += p.y; s.z += p.z; s.w += p.w;
        }
        float4 bb = *(const float4*)(bp + c0);
        float v0 = s.x + bb.x;
        float v1 = s.y + bb.y;
        float v2 = s.z + bb.z;
        float v3 = s.w + bb.w;
        float sm = v0 + v1 + v2 + v3;
        float sq = v0 * v0 + v1 * v1 + v2 * v2 + v3 * v3;
        #pragma unroll
        for (int off = 32; off > 0; off >>= 1) {
            sm += __shfl_xor(sm, off);
            sq += __shfl_xor(sq, off);
        }
        float mu   = sm * (1.0f / 256.0f);
        float var  = fmaxf(sq * (1.0f / 256.0f) - mu * mu, 0.0f);
        float rstd = 1.0f / sqrtf(var + 1e-5f);
        float4 gv = *(const float4*)(gvec + c0);
        float4 bv = *(const float4*)(bvec + c0);
        float4 o;
        o.x = (v0 - mu) * rstd * gv.x + bv.x;
        o.y = (v1 - mu) * rstd * gv.y + bv.y;
        o.z = (v2 - mu) * rstd * gv.z + bv.z;
        o.w = (v3 - mu) * rstd * gv.w + bv.w;
        *(float4*)(out + ((size_t)b * MAXK + h8 * 8 + wv) * DD + c0) = o;
    }
}

extern "C" void kernel_launch(void* const* d_in, const int* in_sizes, int n_in,
                              void* d_out, int out_size, void* d_ws, size_t ws_size,
                              hipStream_t stream) {
    const float* grid_emb = (const float*)d_in[0];
    const int*   grid     = (const int*)d_in[1];
    const float* srep     = (const float*)d_in[2];
    const float* W1v = (const float*)d_in[3];
    const float* b1v = (const float*)d_in[4];
    const float* W2v = (const float*)d_in[5];
    const float* b2v = (const float*)d_in[6];
    const float* Wpv = (const float*)d_in[7];
    const float* bpv = (const float*)d_in[8];
    const float* gv  = (const float*)d_in[9];
    const float* bv  = (const float*)d_in[10];
    const float* osv = (const float*)d_in[11];
    float* out = (float*)d_out;

    const int B  = in_sizes[1] / HW;
    const int KS = in_sizes[2] / (B * DD);

    hipLaunchKernelGGL(ccce_fused, dim3(B * 2), dim3(512), 0, stream,
                       grid_emb, grid, srep, W1v, b1v, W2v, b2v, Wpv, bpv,
                       gv, bv, osv, out, KS);
}